// Round 16
// baseline (252.430 us; speedup 1.0000x reference)
//
#include <hip/hip_runtime.h>

// Problem constants (from setup_inputs): B=32, N=16, M=28, H=W=1024
constexpr int Bc  = 32;
constexpr int Nc  = 16;
constexpr int Mc  = 28;
constexpr int MPc = 30;    // padded mask size M+2
constexpr int Hc  = 1024;
constexpr int Wc  = 1024;
constexpr int ROWS = 8;    // rows per main-kernel block

// d_ws layout:
//   int4   rect[512]            @ 0       (8 KB)   expanded int boxes
//   float2 scale[512]           @ 8192    (4 KB)   (Mp/w, Mp/h)
//   u16    rowmask[32][1024]    @ 12288   (64 KB)  per-row coverage bits
//   u16    colmask[32][1024]    @ 77824   (64 KB)  per-col coverage bits

// Prep: one block per image. Computes expanded rects + scales (single source
// of the trunc math) and the per-position coverage masks.
__global__ __launch_bounds__(256)
void prep_kernel(const float* __restrict__ rects,
                 int4* __restrict__ rectbuf,
                 float2* __restrict__ scalebuf,
                 unsigned short* __restrict__ rowmaskbuf,
                 unsigned short* __restrict__ colmaskbuf)
{
    const int b   = blockIdx.x;
    const int tid = threadIdx.x;
    __shared__ int4 s_rect[Nc];

    if (tid < Nc) {
        const float* r = rects + (b * Nc + tid) * 4;
        const float x0 = r[0], y0 = r[1], x1 = r[2], y1 = r[3];
        const float hs = 0.5357142857142857f;    // 0.5*(M+2)/M
        const float w_half = (x1 - x0) * hs;
        const float h_half = (y1 - y0) * hs;
        const float xc = (x1 + x0) * 0.5f;
        const float yc = (y1 + y0) * 0.5f;
        const int4 rc = make_int4((int)truncf(xc - w_half),    // row begin
                                  (int)truncf(yc - h_half),    // col begin
                                  (int)truncf(xc + w_half),    // row end
                                  (int)truncf(yc + h_half));   // col end
        s_rect[tid] = rc;
        rectbuf[b * Nc + tid] = rc;
        const float w = fmaxf((float)(rc.z - rc.x + 1), 1.0f);
        const float h = fmaxf((float)(rc.w - rc.y + 1), 1.0f);
        scalebuf[b * Nc + tid] = make_float2((float)MPc / w, (float)MPc / h);
    }
    __syncthreads();

    #pragma unroll
    for (int i = 0; i < 4; ++i) {
        const int pos = tid + i * 256;           // 0..1023, coalesced
        unsigned rm = 0, cm = 0;
        #pragma unroll
        for (int k = 0; k < Nc; ++k) {
            const int4 rc = s_rect[k];
            if (pos >= rc.x && pos <= rc.z) rm |= (1u << k);
            if (pos >= rc.y && pos <= rc.w) cm |= (1u << k);
        }
        rowmaskbuf[b * Hc + pos] = (unsigned short)rm;
        colmaskbuf[b * Wc + pos] = (unsigned short)cm;
    }
}

// Main: fused fill+paste, one streaming pass, each output byte written once.
// Block = (image, 8-row band). Setup is a handful of coalesced loads + one
// barrier; hot loop per row: rowmask broadcast, winner = 31-clz(cm & rm),
// covered -> 4-tap bilinear from L2-resident mask, else -1; float4 store.
__global__ __launch_bounds__(256)
void paste_fused_kernel(const float* __restrict__ masks,
                        const int4* __restrict__ rectbuf,
                        const float2* __restrict__ scalebuf,
                        const unsigned short* __restrict__ rowmaskbuf,
                        const unsigned short* __restrict__ colmaskbuf,
                        float* __restrict__ out)
{
    const int bid  = blockIdx.x;                 // b*128 + band
    const int b    = bid >> 7;
    const int row0 = (bid & 127) * ROWS;
    const int tid  = threadIdx.x;

    __shared__ int4           s_rect[Nc];
    __shared__ float2         s_scale[Nc];
    __shared__ unsigned short s_rm[ROWS];

    if (tid < Nc) {
        s_rect[tid]  = rectbuf[b * Nc + tid];
        s_scale[tid] = scalebuf[b * Nc + tid];
    }
    if (tid < ROWS) s_rm[tid] = rowmaskbuf[b * Hc + row0 + tid];

    const int col0 = tid * 4;
    // 4 consecutive u16 colmasks as one aligned u64 load (coalesced)
    const unsigned long long cm4 =
        *(const unsigned long long*)(colmaskbuf + b * Wc + col0);
    __syncthreads();

    const float* mbase = masks + (size_t)b * (Nc * Mc * Mc);
    float* orow = out + (size_t)b * Hc * Wc + (size_t)row0 * Wc;

    for (int rr = 0; rr < ROWS; ++rr) {
        const unsigned rm  = s_rm[rr];           // LDS broadcast
        const int      row = row0 + rr;
        float4 v;
        float* vp = (float*)&v;
        #pragma unroll
        for (int c = 0; c < 4; ++c) {
            const unsigned m = ((unsigned)(cm4 >> (16 * c)) & 0xFFFFu) & rm;
            float val = -1.0f;
            if (m) {
                const int    n  = 31 - __clz((int)m);   // last writer wins
                const int4   rc = s_rect[n];
                const float2 sc = s_scale[n];

                float sx = ((float)(row - rc.x) + 0.5f) * sc.x - 0.5f;
                sx = fminf(fmaxf(sx, 0.0f), (float)(MPc - 1));
                const int   i0 = (int)floorf(sx);
                const float tx = sx - (float)i0;
                const int   i1 = min(i0 + 1, MPc - 1);

                const int col = col0 + c;
                float sy = ((float)(col - rc.y) + 0.5f) * sc.y - 0.5f;
                sy = fminf(fmaxf(sy, 0.0f), (float)(MPc - 1));
                const int   j0 = (int)floorf(sy);
                const float ty = sy - (float)j0;
                const int   j1 = min(j0 + 1, MPc - 1);

                const float* mp = mbase + n * (Mc * Mc);
                const bool iok0 = (i0 >= 1) & (i0 <= Mc);
                const bool iok1 = (i1 >= 1) & (i1 <= Mc);
                const bool jok0 = (j0 >= 1) & (j0 <= Mc);
                const bool jok1 = (j1 >= 1) & (j1 <= Mc);
                // padded-mask taps: interior -> (mask+1)*0.5, pad -> 0
                const float m00 = (iok0 & jok0) ? (mp[(i0-1)*Mc + (j0-1)] + 1.0f) * 0.5f : 0.0f;
                const float m10 = (iok1 & jok0) ? (mp[(i1-1)*Mc + (j0-1)] + 1.0f) * 0.5f : 0.0f;
                const float m01 = (iok0 & jok1) ? (mp[(i0-1)*Mc + (j1-1)] + 1.0f) * 0.5f : 0.0f;
                const float m11 = (iok1 & jok1) ? (mp[(i1-1)*Mc + (j1-1)] + 1.0f) * 0.5f : 0.0f;
                // same op order as reference: row-lerp, then col-lerp
                const float a0 = m00 * (1.0f - tx) + m10 * tx;
                const float a1 = m01 * (1.0f - tx) + m11 * tx;
                val = (a0 * (1.0f - ty) + a1 * ty) * 2.0f - 1.0f;
            }
            vp[c] = val;
        }
        *((float4*)(orow + (size_t)rr * Wc) + tid) = v;
    }
}

extern "C" void kernel_launch(void* const* d_in, const int* in_sizes, int n_in,
                              void* d_out, int out_size, void* d_ws, size_t ws_size,
                              hipStream_t stream) {
    const float* masks = (const float*)d_in[0];   // [B,N,1,M,M]
    const float* rects = (const float*)d_in[1];   // [B,N,4]
    float* out = (float*)d_out;                   // [B,1,H,W]

    int4*           rectbuf  = (int4*)d_ws;
    float2*         scalebuf = (float2*)((char*)d_ws + 8192);
    unsigned short* rowmaskb = (unsigned short*)((char*)d_ws + 12288);
    unsigned short* colmaskb = (unsigned short*)((char*)d_ws + 77824);

    prep_kernel<<<Bc, 256, 0, stream>>>(rects, rectbuf, scalebuf,
                                        rowmaskb, colmaskb);

    paste_fused_kernel<<<Bc * (Hc / ROWS), 256, 0, stream>>>(
        masks, rectbuf, scalebuf, rowmaskb, colmaskb, out);
}